// Round 16
// baseline (184.718 us; speedup 1.0000x reference)
//
#include <hip/hip_runtime.h>
#include <math.h>

static constexpr int N_NODES = 100000;
static constexpr int N_EDGES = 3200000;
static constexpr int F_INC   = 256;
static constexpr int HIDC    = 16;
static constexpr int NCLS    = 32;

static constexpr int BNODES  = 256;
static constexpr int NBKT    = (N_NODES + BNODES - 1) / BNODES;  // 391
static constexpr int CAP     = 9216;
static constexpr int CHUNK   = 4096;
static constexpr int NCHUNK  = (N_EDGES + CHUNK - 1) / CHUNK;    // 782
static constexpr int NTILES  = N_NODES / 16;                     // 6250
static constexpr int GLIN1   = (NTILES + 3) / 4;                 // 1563
static constexpr int NRANK   = NBKT * BNODES;                    // 100096

typedef __attribute__((ext_vector_type(8))) short bf16x8;
typedef __attribute__((ext_vector_type(4))) float f32x4;

__device__ __forceinline__ unsigned pack_bf2(float a, float b) {
    unsigned ua = __float_as_uint(a);
    unsigned ub = __float_as_uint(b);
    ua = (ua + 0x7FFFu + ((ua >> 16) & 1u)) >> 16;
    ub = (ub + 0x7FFFu + ((ub >> 16) & 1u)) & 0xFFFF0000u;
    return ua | ub;
}
__device__ __forceinline__ float bflo(unsigned v) { return __uint_as_float(v << 16); }
__device__ __forceinline__ float bfhi(unsigned v) { return __uint_as_float(v & 0xFFFF0000u); }
__device__ __forceinline__ float elu1(float t) { return t > 0.f ? t : expm1f(t); }

__global__ void k_zero_cur(int* gcur) {
    int i = threadIdx.x;
    if (i < NBKT) gcur[i] = 0;
}

// Bin a chunk of 4096 edges by dst bucket in LDS, flush bucket-sorted runs to the slab.
__global__ __launch_bounds__(256) void k_bucket(const int* __restrict__ src,
                                                const int* __restrict__ dst,
                                                int* gcur, unsigned int* __restrict__ slab) {
    __shared__ int hist[512];
    __shared__ int sc[512];
    __shared__ int place[512];
    __shared__ int gbase[512];
    __shared__ unsigned int staging[CHUNK];
    __shared__ unsigned short bid[CHUNK];
    int tid = threadIdx.x;
    int e0 = blockIdx.x * CHUNK;
    int n = min(CHUNK, N_EDGES - e0);
    hist[tid] = 0; hist[tid + 256] = 0;
    __syncthreads();
    unsigned int pay[16];
    int bk[16];
    #pragma unroll
    for (int r = 0; r < 16; ++r) {
        int i = r * 256 + tid;
        bk[r] = -1;
        if (i < n) {
            int e = e0 + i;
            int s = src[e];
            int t = dst[e];
            int b = t >> 8;
            pay[r] = (unsigned)s | ((unsigned)(t & 255) << 24);
            bk[r] = b;
            atomicAdd(&hist[b], 1);
        }
    }
    __syncthreads();
    sc[tid] = hist[tid]; sc[tid + 256] = hist[tid + 256];
    __syncthreads();
    for (int off = 1; off < 512; off <<= 1) {
        int i0 = tid, i1 = tid + 256;
        int v0 = (i0 >= off) ? sc[i0 - off] : 0;
        int v1 = (i1 >= off) ? sc[i1 - off] : 0;
        __syncthreads();
        sc[i0] += v0; sc[i1] += v1;
        __syncthreads();
    }
    {
        int b0 = tid, b1 = tid + 256;
        int o0 = sc[b0] - hist[b0];
        int o1 = sc[b1] - hist[b1];
        place[b0] = o0; place[b1] = o1;
        sc[b0] = o0; sc[b1] = o1;
        if (b0 < NBKT && hist[b0]) gbase[b0] = atomicAdd(&gcur[b0], hist[b0]);
        if (b1 < NBKT && hist[b1]) gbase[b1] = atomicAdd(&gcur[b1], hist[b1]);
    }
    __syncthreads();
    #pragma unroll
    for (int r = 0; r < 16; ++r) {
        if (bk[r] >= 0) {
            int p = atomicAdd(&place[bk[r]], 1);
            staging[p] = pay[r];
            bid[p] = (unsigned short)bk[r];
        }
    }
    __syncthreads();
    for (int i = tid; i < n; i += 256) {
        int b = bid[i];
        int gp = gbase[b] + (i - sc[b]);
        if (gp < CAP) slab[(size_t)b * CAP + gp] = staging[i];
    }
}

// Per bucket: histogram local dst, scan, reorder in LDS, write back in place.
__global__ __launch_bounds__(512) void k_csr(const int* __restrict__ gcur,
                                             unsigned int* __restrict__ slab,
                                             int* __restrict__ rowptr,
                                             int* __restrict__ cnt,
                                             float* __restrict__ dis) {
    __shared__ int hist[BNODES];
    __shared__ int lofs[BNODES];
    __shared__ int place[BNODES];
    __shared__ unsigned int reord[CAP];
    int tid = threadIdx.x, b = blockIdx.x;
    if (tid < BNODES) hist[tid] = 0;
    __syncthreads();
    int count = min(gcur[b], CAP);
    unsigned int* sl = slab + (size_t)b * CAP;
    for (int i = tid; i < count; i += 512) atomicAdd(&hist[sl[i] >> 24], 1);
    __syncthreads();
    if (tid < BNODES) lofs[tid] = hist[tid];
    __syncthreads();
    for (int off = 1; off < BNODES; off <<= 1) {
        int v = 0;
        if (tid < BNODES && tid >= off) v = lofs[tid - off];
        __syncthreads();
        if (tid < BNODES) lofs[tid] += v;
        __syncthreads();
    }
    if (tid < BNODES) {
        int ex = lofs[tid] - hist[tid];
        lofs[tid] = ex;
        place[tid] = ex;
        int node = b * BNODES + tid;
        if (node < N_NODES) {
            rowptr[node] = b * CAP + ex;
            cnt[node] = hist[tid];
            dis[node] = rsqrtf((float)hist[tid] + 1.0f);
        }
    }
    __syncthreads();
    for (int i = tid; i < count; i += 512) {
        unsigned int v = sl[i];
        int dl = v >> 24;
        int p = atomicAdd(&place[dl], 1);
        reord[p] = v & 0xFFFFFFu;
    }
    __syncthreads();
    for (int i = tid; i < count; i += 512) sl[i] = reord[i];
}

// Counting-sort each bucket's 256 nodes by degree -> nodeperm (rank order).
// Waves processing consecutive ranks then see near-uniform degrees.
__global__ __launch_bounds__(256) void k_perm(const int* __restrict__ cnt,
                                              int* __restrict__ nodeperm) {
    __shared__ int dhist[256];
    __shared__ int dofs[256];
    __shared__ int dplace[256];
    int tid = threadIdx.x, b = blockIdx.x;
    int node = b * BNODES + tid;
    int deg = (node < N_NODES) ? min(cnt[node], 255) : 0;
    dhist[tid] = 0;
    __syncthreads();
    atomicAdd(&dhist[deg], 1);
    __syncthreads();
    dofs[tid] = dhist[tid];
    __syncthreads();
    for (int off = 1; off < 256; off <<= 1) {
        int v = (tid >= off) ? dofs[tid - off] : 0;
        __syncthreads();
        dofs[tid] += v;
        __syncthreads();
    }
    dplace[tid] = dofs[tid] - dhist[tid];
    __syncthreads();
    int rank = atomicAdd(&dplace[deg], 1);
    nodeperm[b * BNODES + rank] = node;
}

// h1 = x @ W1 via MFMA, pre-scaled by dis[n], packed bf16. (R13-proven.)
__global__ __launch_bounds__(256) void k_linear1(const float* __restrict__ x,
                                                 const float* __restrict__ W1,
                                                 const float* __restrict__ dis,
                                                 unsigned* __restrict__ hb) {
    __shared__ float dtile[4][16][18];
    int tid = threadIdx.x;
    int lane = tid & 63;
    int w = tid >> 6;
    int tile = blockIdx.x * 4 + w;
    if (tile >= NTILES) return;
    int g = lane >> 4;
    int r = lane & 15;
    union { uint4 u; bf16x8 v; } bfr[8];
    #pragma unroll
    for (int m = 0; m < 8; ++m) {
        unsigned uu[4];
        #pragma unroll
        for (int t = 0; t < 4; ++t) {
            int k0 = 32 * m + 8 * g + 2 * t;
            uu[t] = pack_bf2(W1[k0 * HIDC + r], W1[(k0 + 1) * HIDC + r]);
        }
        bfr[m].u = make_uint4(uu[0], uu[1], uu[2], uu[3]);
    }
    const float* xrow = x + (size_t)(tile * 16 + r) * F_INC;
    f32x4 acc = {0.f, 0.f, 0.f, 0.f};
    #pragma unroll
    for (int m = 0; m < 8; ++m) {
        int ks = 32 * m + 8 * g;
        float4 va = *(const float4*)(xrow + ks);
        float4 vb = *(const float4*)(xrow + ks + 4);
        union { uint4 u; bf16x8 v; } af;
        af.u = make_uint4(pack_bf2(va.x, va.y), pack_bf2(va.z, va.w),
                          pack_bf2(vb.x, vb.y), pack_bf2(vb.z, vb.w));
        acc = __builtin_amdgcn_mfma_f32_16x16x32_bf16(af.v, bfr[m].v, acc, 0, 0, 0);
    }
    #pragma unroll
    for (int t = 0; t < 4; ++t) dtile[w][4 * g + t][r] = acc[t];
    __builtin_amdgcn_s_waitcnt(0);
    int q = lane & 7;
    #pragma unroll
    for (int h = 0; h < 2; ++h) {
        int rr = (lane >> 3) + 8 * h;
        int node = tile * 16 + rr;
        float dn = dis[node];
        hb[(size_t)node * 8 + q] =
            pack_bf2(dn * dtile[w][rr][2 * q], dn * dtile[w][rr][2 * q + 1]);
    }
}

// Shared gather core: lane q of node n accumulates agg pair (j = 2q, 2q+1).
__device__ __forceinline__ void gather_core(int base, int deg, int q,
                                            const unsigned* __restrict__ csr,
                                            const unsigned* __restrict__ hb,
                                            unsigned sv, float& acc0, float& acc1) {
    acc0 = bflo(sv); acc1 = bfhi(sv);
    int j = 0;
    for (; j + 3 < deg; j += 4) {
        int s0 = csr[base + j];
        int s1 = csr[base + j + 1];
        int s2 = csr[base + j + 2];
        int s3 = csr[base + j + 3];
        unsigned v0 = hb[(size_t)s0 * 8 + q];
        unsigned v1 = hb[(size_t)s1 * 8 + q];
        unsigned v2 = hb[(size_t)s2 * 8 + q];
        unsigned v3 = hb[(size_t)s3 * 8 + q];
        acc0 += (bflo(v0) + bflo(v1)) + (bflo(v2) + bflo(v3));
        acc1 += (bfhi(v0) + bfhi(v1)) + (bfhi(v2) + bfhi(v3));
    }
    for (; j < deg; ++j) {
        int s = csr[base + j];
        unsigned v = hb[(size_t)s * 8 + q];
        acc0 += bflo(v);
        acc1 += bfhi(v);
    }
}

// Layer-1 gather FUSED with bias+ELU+@W2+prescale-pack (rank-permuted order).
__global__ __launch_bounds__(256) void k_gather_fl1(const int* __restrict__ rowptr,
                                                    const int* __restrict__ cnt,
                                                    const unsigned* __restrict__ csr,
                                                    const float* __restrict__ dis,
                                                    const int* __restrict__ nodeperm,
                                                    const unsigned* __restrict__ hb,
                                                    const float* __restrict__ b1,
                                                    const float* __restrict__ W2,
                                                    unsigned* __restrict__ hb_out) {
    __shared__ float W2s[HIDC * HIDC];
    __shared__ float b1s[HIDC];
    if (threadIdx.x < HIDC * HIDC) W2s[threadIdx.x] = W2[threadIdx.x];
    if (threadIdx.x < HIDC) b1s[threadIdx.x] = b1[threadIdx.x];
    __syncthreads();
    int idx = blockIdx.x * blockDim.x + threadIdx.x;
    int rank = idx >> 3;
    if (rank >= NRANK) return;
    int n = nodeperm[rank];
    if (n >= N_NODES) return;
    int q = idx & 7;
    int lane = threadIdx.x & 63;
    float acc0, acc1;
    gather_core(rowptr[n], cnt[n], q, csr, hb, hb[(size_t)n * 8 + q], acc0, acc1);
    float dn = dis[n];
    float a0 = elu1(acc0 * dn + b1s[2 * q]);
    float a1 = elu1(acc1 * dn + b1s[2 * q + 1]);
    int gb = lane & 56;
    float h0 = 0.f, h1 = 0.f;
    #pragma unroll
    for (int k2 = 0; k2 < 8; ++k2) {
        float e0 = __shfl(a0, gb + k2, 64);
        float e1 = __shfl(a1, gb + k2, 64);
        h0 += e0 * W2s[(2 * k2) * HIDC + 2 * q]     + e1 * W2s[(2 * k2 + 1) * HIDC + 2 * q];
        h1 += e0 * W2s[(2 * k2) * HIDC + 2 * q + 1] + e1 * W2s[(2 * k2 + 1) * HIDC + 2 * q + 1];
    }
    hb_out[(size_t)n * 8 + q] = pack_bf2(dn * h0, dn * h1);
}

// Layer-2 gather: z2 = elu(agg + b2) -> prescaled table (rank-permuted order).
__global__ __launch_bounds__(256) void k_gather_z(const int* __restrict__ rowptr,
                                                  const int* __restrict__ cnt,
                                                  const unsigned* __restrict__ csr,
                                                  const float* __restrict__ dis,
                                                  const int* __restrict__ nodeperm,
                                                  const unsigned* __restrict__ hb,
                                                  const float* __restrict__ bias,
                                                  unsigned* __restrict__ outp) {
    int idx = blockIdx.x * blockDim.x + threadIdx.x;
    int rank = idx >> 3;
    if (rank >= NRANK) return;
    int n = nodeperm[rank];
    if (n >= N_NODES) return;
    int q = idx & 7;
    float acc0, acc1;
    gather_core(rowptr[n], cnt[n], q, csr, hb, hb[(size_t)n * 8 + q], acc0, acc1);
    float dn = dis[n];
    float z0 = elu1(acc0 * dn + bias[2 * q]);
    float z1 = elu1(acc1 * dn + bias[2 * q + 1]);
    outp[(size_t)n * 8 + q] = pack_bf2(dn * z0, dn * z1);
}

// Layer-3 gather FUSED with @W3+bias+ELU+log_softmax (rank-permuted order).
__global__ __launch_bounds__(256) void k_gather_fin(const int* __restrict__ rowptr,
                                                    const int* __restrict__ cnt,
                                                    const unsigned* __restrict__ csr,
                                                    const float* __restrict__ dis,
                                                    const int* __restrict__ nodeperm,
                                                    const unsigned* __restrict__ hb,
                                                    const float* __restrict__ W3,
                                                    const float* __restrict__ b3,
                                                    float* __restrict__ out) {
    __shared__ float W3s[HIDC * NCLS];
    __shared__ float b3s[NCLS];
    for (int i = threadIdx.x; i < HIDC * NCLS; i += 256) W3s[i] = W3[i];
    if (threadIdx.x < NCLS) b3s[threadIdx.x] = b3[threadIdx.x];
    __syncthreads();
    int idx = blockIdx.x * blockDim.x + threadIdx.x;
    int rank = idx >> 3;
    if (rank >= NRANK) return;
    int n = nodeperm[rank];
    if (n >= N_NODES) return;
    int q = idx & 7;
    int lane = threadIdx.x & 63;
    float acc0, acc1;
    gather_core(rowptr[n], cnt[n], q, csr, hb, hb[(size_t)n * 8 + q], acc0, acc1);
    float dn = dis[n];
    float g0 = acc0 * dn, g1 = acc1 * dn;
    int gb = lane & 56;
    int j0 = q * 4;
    float r0 = b3s[j0], r1 = b3s[j0 + 1], r2 = b3s[j0 + 2], r3 = b3s[j0 + 3];
    #pragma unroll
    for (int k2 = 0; k2 < 8; ++k2) {
        float e0 = __shfl(g0, gb + k2, 64);
        float e1 = __shfl(g1, gb + k2, 64);
        const float* wa = &W3s[(2 * k2) * NCLS + j0];
        const float* wb = &W3s[(2 * k2 + 1) * NCLS + j0];
        r0 += e0 * wa[0] + e1 * wb[0];
        r1 += e0 * wa[1] + e1 * wb[1];
        r2 += e0 * wa[2] + e1 * wb[2];
        r3 += e0 * wa[3] + e1 * wb[3];
    }
    r0 = elu1(r0); r1 = elu1(r1); r2 = elu1(r2); r3 = elu1(r3);
    float m = fmaxf(fmaxf(r0, r1), fmaxf(r2, r3));
    #pragma unroll
    for (int off = 1; off < 8; off <<= 1) m = fmaxf(m, __shfl_xor(m, off, 64));
    float s = expf(r0 - m) + expf(r1 - m) + expf(r2 - m) + expf(r3 - m);
    #pragma unroll
    for (int off = 1; off < 8; off <<= 1) s += __shfl_xor(s, off, 64);
    float lse = logf(s) + m;
    float4* o = (float4*)(out + (size_t)n * NCLS + j0);
    *o = make_float4(r0 - lse, r1 - lse, r2 - lse, r3 - lse);
}

extern "C" void kernel_launch(void* const* d_in, const int* in_sizes, int n_in,
                              void* d_out, int out_size, void* d_ws, size_t ws_size,
                              hipStream_t stream) {
    const float* x  = (const float*)d_in[0];
    const int*   ei = (const int*)d_in[1];
    const float* W1 = (const float*)d_in[2];
    const float* b1 = (const float*)d_in[3];
    const float* W2 = (const float*)d_in[4];
    const float* b2 = (const float*)d_in[5];
    const float* W3 = (const float*)d_in[6];
    const float* b3 = (const float*)d_in[7];
    float* out = (float*)d_out;
    const int* src = ei;
    const int* dst = ei + N_EDGES;

    int* wi = (int*)d_ws;
    int*          gcur     = wi;                                 // 512
    unsigned int* slab     = (unsigned int*)(wi + 512);          // NBKT*CAP
    int*          rowptr   = wi + 512 + NBKT * CAP;              // 102,400
    int*          cnt      = rowptr + 102400;                    // 102,400
    float*        dis      = (float*)(cnt + 102400);             // 102,400
    int*          nodeperm = (int*)(dis + 102400);               // 100,352 (pad)
    unsigned*     Bh       = (unsigned*)(nodeperm + 100352);     // 819,200
    unsigned*     Zb       = Bh + 819200;                        // 819,200
    (void)ws_size; (void)n_in; (void)in_sizes; (void)out_size;

    const int GGATH = (int)(((long long)NRANK * 8 + 255) / 256);   // 3128

    k_zero_cur<<<1, 512, 0, stream>>>(gcur);
    k_bucket<<<NCHUNK, 256, 0, stream>>>(src, dst, gcur, slab);
    k_csr<<<NBKT, 512, 0, stream>>>(gcur, slab, rowptr, cnt, dis);
    k_perm<<<NBKT, 256, 0, stream>>>(cnt, nodeperm);

    // Layer 1: h1 = x@W1 via MFMA (pre-scaled bf16) -> gather+bias+ELU+@W2 -> Zb
    k_linear1<<<GLIN1, 256, 0, stream>>>(x, W1, dis, Bh);
    k_gather_fl1<<<GGATH, 256, 0, stream>>>(rowptr, cnt, slab, dis, nodeperm, Bh, b1, W2, Zb);
    // Layer 2: gather -> z2 = elu(agg+b2) -> Bh
    k_gather_z<<<GGATH, 256, 0, stream>>>(rowptr, cnt, slab, dis, nodeperm, Zb, b2, Bh);
    // Layer 3: gather -> @W3+b3 -> ELU -> log_softmax -> out
    k_gather_fin<<<GGATH, 256, 0, stream>>>(rowptr, cnt, slab, dis, nodeperm, Bh, W3, b3, out);
}

// Round 17
// 166.450 us; speedup vs baseline: 1.1098x; 1.1098x over previous
//
#include <hip/hip_runtime.h>
#include <math.h>

static constexpr int N_NODES = 100000;
static constexpr int N_EDGES = 3200000;
static constexpr int F_INC   = 256;
static constexpr int HIDC    = 16;
static constexpr int NCLS    = 32;

static constexpr int BNODES  = 256;
static constexpr int NBKT    = (N_NODES + BNODES - 1) / BNODES;  // 391
static constexpr int CAP     = 9216;
static constexpr int CHUNK   = 4096;
static constexpr int NCHUNK  = (N_EDGES + CHUNK - 1) / CHUNK;    // 782
static constexpr int NTILES  = N_NODES / 16;                     // 6250
static constexpr int GLIN1   = (NTILES + 3) / 4;                 // 1563

typedef __attribute__((ext_vector_type(8))) short bf16x8;
typedef __attribute__((ext_vector_type(4))) float f32x4;

__device__ __forceinline__ unsigned pack_bf2(float a, float b) {
    unsigned ua = __float_as_uint(a);
    unsigned ub = __float_as_uint(b);
    ua = (ua + 0x7FFFu + ((ua >> 16) & 1u)) >> 16;
    ub = (ub + 0x7FFFu + ((ub >> 16) & 1u)) & 0xFFFF0000u;
    return ua | ub;
}
__device__ __forceinline__ float bflo(unsigned v) { return __uint_as_float(v << 16); }
__device__ __forceinline__ float bfhi(unsigned v) { return __uint_as_float(v & 0xFFFF0000u); }
__device__ __forceinline__ float elu1(float t) { return t > 0.f ? t : expm1f(t); }

__global__ void k_zero_cur(int* gcur) {
    int i = threadIdx.x;
    if (i < NBKT) gcur[i] = 0;
}

// Bin a chunk of 4096 edges by dst bucket in LDS, flush bucket-sorted runs to the slab.
__global__ __launch_bounds__(256) void k_bucket(const int* __restrict__ src,
                                                const int* __restrict__ dst,
                                                int* gcur, unsigned int* __restrict__ slab) {
    __shared__ int hist[512];
    __shared__ int sc[512];
    __shared__ int place[512];
    __shared__ int gbase[512];
    __shared__ unsigned int staging[CHUNK];
    __shared__ unsigned short bid[CHUNK];
    int tid = threadIdx.x;
    int e0 = blockIdx.x * CHUNK;
    int n = min(CHUNK, N_EDGES - e0);
    hist[tid] = 0; hist[tid + 256] = 0;
    __syncthreads();
    unsigned int pay[16];
    int bk[16];
    #pragma unroll
    for (int r = 0; r < 16; ++r) {
        int i = r * 256 + tid;
        bk[r] = -1;
        if (i < n) {
            int e = e0 + i;
            int s = src[e];
            int t = dst[e];
            int b = t >> 8;
            pay[r] = (unsigned)s | ((unsigned)(t & 255) << 24);
            bk[r] = b;
            atomicAdd(&hist[b], 1);
        }
    }
    __syncthreads();
    sc[tid] = hist[tid]; sc[tid + 256] = hist[tid + 256];
    __syncthreads();
    for (int off = 1; off < 512; off <<= 1) {
        int i0 = tid, i1 = tid + 256;
        int v0 = (i0 >= off) ? sc[i0 - off] : 0;
        int v1 = (i1 >= off) ? sc[i1 - off] : 0;
        __syncthreads();
        sc[i0] += v0; sc[i1] += v1;
        __syncthreads();
    }
    {
        int b0 = tid, b1 = tid + 256;
        int o0 = sc[b0] - hist[b0];
        int o1 = sc[b1] - hist[b1];
        place[b0] = o0; place[b1] = o1;
        sc[b0] = o0; sc[b1] = o1;
        if (b0 < NBKT && hist[b0]) gbase[b0] = atomicAdd(&gcur[b0], hist[b0]);
        if (b1 < NBKT && hist[b1]) gbase[b1] = atomicAdd(&gcur[b1], hist[b1]);
    }
    __syncthreads();
    #pragma unroll
    for (int r = 0; r < 16; ++r) {
        if (bk[r] >= 0) {
            int p = atomicAdd(&place[bk[r]], 1);
            staging[p] = pay[r];
            bid[p] = (unsigned short)bk[r];
        }
    }
    __syncthreads();
    for (int i = tid; i < n; i += 256) {
        int b = bid[i];
        int gp = gbase[b] + (i - sc[b]);
        if (gp < CAP) slab[(size_t)b * CAP + gp] = staging[i];
    }
}

// Per bucket: histogram local dst, scan, reorder in LDS, write back in place.
__global__ __launch_bounds__(512) void k_csr(const int* __restrict__ gcur,
                                             unsigned int* __restrict__ slab,
                                             int* __restrict__ rowptr,
                                             int* __restrict__ cnt,
                                             float* __restrict__ dis) {
    __shared__ int hist[BNODES];
    __shared__ int lofs[BNODES];
    __shared__ int place[BNODES];
    __shared__ unsigned int reord[CAP];
    int tid = threadIdx.x, b = blockIdx.x;
    if (tid < BNODES) hist[tid] = 0;
    __syncthreads();
    int count = min(gcur[b], CAP);
    unsigned int* sl = slab + (size_t)b * CAP;
    for (int i = tid; i < count; i += 512) atomicAdd(&hist[sl[i] >> 24], 1);
    __syncthreads();
    if (tid < BNODES) lofs[tid] = hist[tid];
    __syncthreads();
    for (int off = 1; off < BNODES; off <<= 1) {
        int v = 0;
        if (tid < BNODES && tid >= off) v = lofs[tid - off];
        __syncthreads();
        if (tid < BNODES) lofs[tid] += v;
        __syncthreads();
    }
    if (tid < BNODES) {
        int ex = lofs[tid] - hist[tid];
        lofs[tid] = ex;
        place[tid] = ex;
        int node = b * BNODES + tid;
        if (node < N_NODES) {
            rowptr[node] = b * CAP + ex;
            cnt[node] = hist[tid];
            dis[node] = rsqrtf((float)hist[tid] + 1.0f);
        }
    }
    __syncthreads();
    for (int i = tid; i < count; i += 512) {
        unsigned int v = sl[i];
        int dl = v >> 24;
        int p = atomicAdd(&place[dl], 1);
        reord[p] = v & 0xFFFFFFu;
    }
    __syncthreads();
    for (int i = tid; i < count; i += 512) sl[i] = reord[i];
}

// h1 = x @ W1 via MFMA, pre-scaled by dis[n], packed bf16.
// R17 change: BURST-issue all 16 x float4 loads into registers BEFORE the
// pack/MFMA chain -> one HBM latency exposure instead of eight.
__global__ __launch_bounds__(256) void k_linear1(const float* __restrict__ x,
                                                 const float* __restrict__ W1,
                                                 const float* __restrict__ dis,
                                                 unsigned* __restrict__ hb) {
    __shared__ float dtile[4][16][18];
    int tid = threadIdx.x;
    int lane = tid & 63;
    int w = tid >> 6;
    int tile = blockIdx.x * 4 + w;
    if (tile >= NTILES) return;
    int g = lane >> 4;
    int r = lane & 15;
    const float* xrow = x + (size_t)(tile * 16 + r) * F_INC;
    // burst: all 16 loads issued back-to-back (64 VGPRs of x data in flight)
    float4 xa[8], xb[8];
    #pragma unroll
    for (int m = 0; m < 8; ++m) {
        int ks = 32 * m + 8 * g;
        xa[m] = *(const float4*)(xrow + ks);
        xb[m] = *(const float4*)(xrow + ks + 4);
    }
    // B fragments (L1-hot W1; loads overlap the x burst latency)
    union { uint4 u; bf16x8 v; } bfr[8];
    #pragma unroll
    for (int m = 0; m < 8; ++m) {
        unsigned uu[4];
        #pragma unroll
        for (int t = 0; t < 4; ++t) {
            int k0 = 32 * m + 8 * g + 2 * t;
            uu[t] = pack_bf2(W1[k0 * HIDC + r], W1[(k0 + 1) * HIDC + r]);
        }
        bfr[m].u = make_uint4(uu[0], uu[1], uu[2], uu[3]);
    }
    f32x4 acc = {0.f, 0.f, 0.f, 0.f};
    #pragma unroll
    for (int m = 0; m < 8; ++m) {
        union { uint4 u; bf16x8 v; } af;
        af.u = make_uint4(pack_bf2(xa[m].x, xa[m].y), pack_bf2(xa[m].z, xa[m].w),
                          pack_bf2(xb[m].x, xb[m].y), pack_bf2(xb[m].z, xb[m].w));
        acc = __builtin_amdgcn_mfma_f32_16x16x32_bf16(af.v, bfr[m].v, acc, 0, 0, 0);
    }
    #pragma unroll
    for (int t = 0; t < 4; ++t) dtile[w][4 * g + t][r] = acc[t];
    __builtin_amdgcn_s_waitcnt(0);
    int q = lane & 7;
    #pragma unroll
    for (int h = 0; h < 2; ++h) {
        int rr = (lane >> 3) + 8 * h;
        int node = tile * 16 + rr;
        float dn = dis[node];
        hb[(size_t)node * 8 + q] =
            pack_bf2(dn * dtile[w][rr][2 * q], dn * dtile[w][rr][2 * q + 1]);
    }
}

// Shared gather core: lane q of node n accumulates agg pair (j = 2q, 2q+1).
__device__ __forceinline__ void gather_core(int base, int deg, int q,
                                            const unsigned* __restrict__ csr,
                                            const unsigned* __restrict__ hb,
                                            unsigned sv, float& acc0, float& acc1) {
    acc0 = bflo(sv); acc1 = bfhi(sv);
    int j = 0;
    for (; j + 3 < deg; j += 4) {
        int s0 = csr[base + j];
        int s1 = csr[base + j + 1];
        int s2 = csr[base + j + 2];
        int s3 = csr[base + j + 3];
        unsigned v0 = hb[(size_t)s0 * 8 + q];
        unsigned v1 = hb[(size_t)s1 * 8 + q];
        unsigned v2 = hb[(size_t)s2 * 8 + q];
        unsigned v3 = hb[(size_t)s3 * 8 + q];
        acc0 += (bflo(v0) + bflo(v1)) + (bflo(v2) + bflo(v3));
        acc1 += (bfhi(v0) + bfhi(v1)) + (bfhi(v2) + bfhi(v3));
    }
    for (; j < deg; ++j) {
        int s = csr[base + j];
        unsigned v = hb[(size_t)s * 8 + q];
        acc0 += bflo(v);
        acc1 += bfhi(v);
    }
}

// Layer-1 gather FUSED with bias+ELU+@W2+prescale-pack: writes next bf16 table.
__global__ __launch_bounds__(256) void k_gather_fl1(const int* __restrict__ rowptr,
                                                    const int* __restrict__ cnt,
                                                    const unsigned* __restrict__ csr,
                                                    const float* __restrict__ dis,
                                                    const unsigned* __restrict__ hb,
                                                    const float* __restrict__ b1,
                                                    const float* __restrict__ W2,
                                                    unsigned* __restrict__ hb_out) {
    __shared__ float W2s[HIDC * HIDC];
    __shared__ float b1s[HIDC];
    if (threadIdx.x < HIDC * HIDC) W2s[threadIdx.x] = W2[threadIdx.x];
    if (threadIdx.x < HIDC) b1s[threadIdx.x] = b1[threadIdx.x];
    __syncthreads();
    int idx = blockIdx.x * blockDim.x + threadIdx.x;
    int n = idx >> 3;
    if (n >= N_NODES) return;
    int q = idx & 7;
    int lane = threadIdx.x & 63;
    float acc0, acc1;
    gather_core(rowptr[n], cnt[n], q, csr, hb, hb[(size_t)n * 8 + q], acc0, acc1);
    float dn = dis[n];
    float a0 = elu1(acc0 * dn + b1s[2 * q]);
    float a1 = elu1(acc1 * dn + b1s[2 * q + 1]);
    int gb = lane & 56;
    float h0 = 0.f, h1 = 0.f;
    #pragma unroll
    for (int k2 = 0; k2 < 8; ++k2) {
        float e0 = __shfl(a0, gb + k2, 64);
        float e1 = __shfl(a1, gb + k2, 64);
        h0 += e0 * W2s[(2 * k2) * HIDC + 2 * q]     + e1 * W2s[(2 * k2 + 1) * HIDC + 2 * q];
        h1 += e0 * W2s[(2 * k2) * HIDC + 2 * q + 1] + e1 * W2s[(2 * k2 + 1) * HIDC + 2 * q + 1];
    }
    hb_out[(size_t)n * 8 + q] = pack_bf2(dn * h0, dn * h1);
}

// Layer-2 gather: z2 = elu(agg + b2), stored pre-scaled bf16 (next table).
__global__ __launch_bounds__(256) void k_gather_z(const int* __restrict__ rowptr,
                                                  const int* __restrict__ cnt,
                                                  const unsigned* __restrict__ csr,
                                                  const float* __restrict__ dis,
                                                  const unsigned* __restrict__ hb,
                                                  const float* __restrict__ bias,
                                                  unsigned* __restrict__ outp) {
    int idx = blockIdx.x * blockDim.x + threadIdx.x;
    int n = idx >> 3;
    if (n >= N_NODES) return;
    int q = idx & 7;
    float acc0, acc1;
    gather_core(rowptr[n], cnt[n], q, csr, hb, hb[(size_t)n * 8 + q], acc0, acc1);
    float dn = dis[n];
    float z0 = elu1(acc0 * dn + bias[2 * q]);
    float z1 = elu1(acc1 * dn + bias[2 * q + 1]);
    outp[(size_t)n * 8 + q] = pack_bf2(dn * z0, dn * z1);
}

// Layer-3 gather FUSED with @W3+bias+ELU+log_softmax: writes out directly.
__global__ __launch_bounds__(256) void k_gather_fin(const int* __restrict__ rowptr,
                                                    const int* __restrict__ cnt,
                                                    const unsigned* __restrict__ csr,
                                                    const float* __restrict__ dis,
                                                    const unsigned* __restrict__ hb,
                                                    const float* __restrict__ W3,
                                                    const float* __restrict__ b3,
                                                    float* __restrict__ out) {
    __shared__ float W3s[HIDC * NCLS];
    __shared__ float b3s[NCLS];
    for (int i = threadIdx.x; i < HIDC * NCLS; i += 256) W3s[i] = W3[i];
    if (threadIdx.x < NCLS) b3s[threadIdx.x] = b3[threadIdx.x];
    __syncthreads();
    int idx = blockIdx.x * blockDim.x + threadIdx.x;
    int n = idx >> 3;
    if (n >= N_NODES) return;
    int q = idx & 7;
    int lane = threadIdx.x & 63;
    float acc0, acc1;
    gather_core(rowptr[n], cnt[n], q, csr, hb, hb[(size_t)n * 8 + q], acc0, acc1);
    float dn = dis[n];
    float g0 = acc0 * dn, g1 = acc1 * dn;
    int gb = lane & 56;
    int j0 = q * 4;
    float r0 = b3s[j0], r1 = b3s[j0 + 1], r2 = b3s[j0 + 2], r3 = b3s[j0 + 3];
    #pragma unroll
    for (int k2 = 0; k2 < 8; ++k2) {
        float e0 = __shfl(g0, gb + k2, 64);
        float e1 = __shfl(g1, gb + k2, 64);
        const float* wa = &W3s[(2 * k2) * NCLS + j0];
        const float* wb = &W3s[(2 * k2 + 1) * NCLS + j0];
        r0 += e0 * wa[0] + e1 * wb[0];
        r1 += e0 * wa[1] + e1 * wb[1];
        r2 += e0 * wa[2] + e1 * wb[2];
        r3 += e0 * wa[3] + e1 * wb[3];
    }
    r0 = elu1(r0); r1 = elu1(r1); r2 = elu1(r2); r3 = elu1(r3);
    float m = fmaxf(fmaxf(r0, r1), fmaxf(r2, r3));
    #pragma unroll
    for (int off = 1; off < 8; off <<= 1) m = fmaxf(m, __shfl_xor(m, off, 64));
    float s = expf(r0 - m) + expf(r1 - m) + expf(r2 - m) + expf(r3 - m);
    #pragma unroll
    for (int off = 1; off < 8; off <<= 1) s += __shfl_xor(s, off, 64);
    float lse = logf(s) + m;
    float4* o = (float4*)(out + (size_t)n * NCLS + j0);
    *o = make_float4(r0 - lse, r1 - lse, r2 - lse, r3 - lse);
}

extern "C" void kernel_launch(void* const* d_in, const int* in_sizes, int n_in,
                              void* d_out, int out_size, void* d_ws, size_t ws_size,
                              hipStream_t stream) {
    const float* x  = (const float*)d_in[0];
    const int*   ei = (const int*)d_in[1];
    const float* W1 = (const float*)d_in[2];
    const float* b1 = (const float*)d_in[3];
    const float* W2 = (const float*)d_in[4];
    const float* b2 = (const float*)d_in[5];
    const float* W3 = (const float*)d_in[6];
    const float* b3 = (const float*)d_in[7];
    float* out = (float*)d_out;
    const int* src = ei;
    const int* dst = ei + N_EDGES;

    int* wi = (int*)d_ws;
    int*          gcur   = wi;                                   // 512
    unsigned int* slab   = (unsigned int*)(wi + 512);            // NBKT*CAP
    int*          rowptr = wi + 512 + NBKT * CAP;                // 102,400
    int*          cnt    = rowptr + 102400;                      // 102,400
    float*        dis    = (float*)(cnt + 102400);               // 102,400
    unsigned*     Bh     = (unsigned*)(dis + 102400);            // 819,200
    unsigned*     Zb     = Bh + 819200;                          // 819,200
    (void)ws_size; (void)n_in; (void)in_sizes; (void)out_size;

    const int GGATH = (int)(((long long)N_NODES * 8 + 255) / 256);   // 3125

    k_zero_cur<<<1, 512, 0, stream>>>(gcur);
    k_bucket<<<NCHUNK, 256, 0, stream>>>(src, dst, gcur, slab);
    k_csr<<<NBKT, 512, 0, stream>>>(gcur, slab, rowptr, cnt, dis);

    // Layer 1: h1 = x@W1 via MFMA (pre-scaled bf16) -> gather+bias+ELU+@W2 -> Zb
    k_linear1<<<GLIN1, 256, 0, stream>>>(x, W1, dis, Bh);
    k_gather_fl1<<<GGATH, 256, 0, stream>>>(rowptr, cnt, slab, dis, Bh, b1, W2, Zb);
    // Layer 2: gather -> z2 = elu(agg+b2) -> Bh
    k_gather_z<<<GGATH, 256, 0, stream>>>(rowptr, cnt, slab, dis, Zb, b2, Bh);
    // Layer 3: gather -> @W3+b3 -> ELU -> log_softmax -> out
    k_gather_fin<<<GGATH, 256, 0, stream>>>(rowptr, cnt, slab, dis, Bh, W3, b3, out);
}

// Round 18
// 161.923 us; speedup vs baseline: 1.1408x; 1.0280x over previous
//
#include <hip/hip_runtime.h>
#include <math.h>

static constexpr int N_NODES = 100000;
static constexpr int N_EDGES = 3200000;
static constexpr int F_INC   = 256;
static constexpr int HIDC    = 16;
static constexpr int NCLS    = 32;

static constexpr int BNODES  = 256;
static constexpr int NBKT    = (N_NODES + BNODES - 1) / BNODES;  // 391
static constexpr int CAP     = 9216;
static constexpr int CHUNK   = 4096;
static constexpr int NCHUNK  = (N_EDGES + CHUNK - 1) / CHUNK;    // 782
static constexpr int NTILES  = N_NODES / 16;                     // 6250
static constexpr int GLIN1   = (NTILES + 3) / 4;                 // 1563

typedef __attribute__((ext_vector_type(8))) short bf16x8;
typedef __attribute__((ext_vector_type(4))) float f32x4;

__device__ __forceinline__ unsigned pack_bf2(float a, float b) {
    unsigned ua = __float_as_uint(a);
    unsigned ub = __float_as_uint(b);
    ua = (ua + 0x7FFFu + ((ua >> 16) & 1u)) >> 16;
    ub = (ub + 0x7FFFu + ((ub >> 16) & 1u)) & 0xFFFF0000u;
    return ua | ub;
}
__device__ __forceinline__ float bflo(unsigned v) { return __uint_as_float(v << 16); }
__device__ __forceinline__ float bfhi(unsigned v) { return __uint_as_float(v & 0xFFFF0000u); }
__device__ __forceinline__ float elu1(float t) { return t > 0.f ? t : expm1f(t); }

__global__ void k_zero_cur(int* gcur) {
    int i = threadIdx.x;
    if (i < NBKT) gcur[i] = 0;
}

// Bin a chunk of 4096 edges by dst bucket in LDS, flush bucket-sorted runs to the slab.
__global__ __launch_bounds__(256) void k_bucket(const int* __restrict__ src,
                                                const int* __restrict__ dst,
                                                int* gcur, unsigned int* __restrict__ slab) {
    __shared__ int hist[512];
    __shared__ int sc[512];
    __shared__ int place[512];
    __shared__ int gbase[512];
    __shared__ unsigned int staging[CHUNK];
    __shared__ unsigned short bid[CHUNK];
    int tid = threadIdx.x;
    int e0 = blockIdx.x * CHUNK;
    int n = min(CHUNK, N_EDGES - e0);
    hist[tid] = 0; hist[tid + 256] = 0;
    __syncthreads();
    unsigned int pay[16];
    int bk[16];
    #pragma unroll
    for (int r = 0; r < 16; ++r) {
        int i = r * 256 + tid;
        bk[r] = -1;
        if (i < n) {
            int e = e0 + i;
            int s = src[e];
            int t = dst[e];
            int b = t >> 8;
            pay[r] = (unsigned)s | ((unsigned)(t & 255) << 24);
            bk[r] = b;
            atomicAdd(&hist[b], 1);
        }
    }
    __syncthreads();
    sc[tid] = hist[tid]; sc[tid + 256] = hist[tid + 256];
    __syncthreads();
    for (int off = 1; off < 512; off <<= 1) {
        int i0 = tid, i1 = tid + 256;
        int v0 = (i0 >= off) ? sc[i0 - off] : 0;
        int v1 = (i1 >= off) ? sc[i1 - off] : 0;
        __syncthreads();
        sc[i0] += v0; sc[i1] += v1;
        __syncthreads();
    }
    {
        int b0 = tid, b1 = tid + 256;
        int o0 = sc[b0] - hist[b0];
        int o1 = sc[b1] - hist[b1];
        place[b0] = o0; place[b1] = o1;
        sc[b0] = o0; sc[b1] = o1;
        if (b0 < NBKT && hist[b0]) gbase[b0] = atomicAdd(&gcur[b0], hist[b0]);
        if (b1 < NBKT && hist[b1]) gbase[b1] = atomicAdd(&gcur[b1], hist[b1]);
    }
    __syncthreads();
    #pragma unroll
    for (int r = 0; r < 16; ++r) {
        if (bk[r] >= 0) {
            int p = atomicAdd(&place[bk[r]], 1);
            staging[p] = pay[r];
            bid[p] = (unsigned short)bk[r];
        }
    }
    __syncthreads();
    for (int i = tid; i < n; i += 256) {
        int b = bid[i];
        int gp = gbase[b] + (i - sc[b]);
        if (gp < CAP) slab[(size_t)b * CAP + gp] = staging[i];
    }
}

// Per bucket: histogram local dst, scan, reorder in LDS, write back in place.
__global__ __launch_bounds__(512) void k_csr(const int* __restrict__ gcur,
                                             unsigned int* __restrict__ slab,
                                             int* __restrict__ rowptr,
                                             int* __restrict__ cnt,
                                             float* __restrict__ dis) {
    __shared__ int hist[BNODES];
    __shared__ int lofs[BNODES];
    __shared__ int place[BNODES];
    __shared__ unsigned int reord[CAP];
    int tid = threadIdx.x, b = blockIdx.x;
    if (tid < BNODES) hist[tid] = 0;
    __syncthreads();
    int count = min(gcur[b], CAP);
    unsigned int* sl = slab + (size_t)b * CAP;
    for (int i = tid; i < count; i += 512) atomicAdd(&hist[sl[i] >> 24], 1);
    __syncthreads();
    if (tid < BNODES) lofs[tid] = hist[tid];
    __syncthreads();
    for (int off = 1; off < BNODES; off <<= 1) {
        int v = 0;
        if (tid < BNODES && tid >= off) v = lofs[tid - off];
        __syncthreads();
        if (tid < BNODES) lofs[tid] += v;
        __syncthreads();
    }
    if (tid < BNODES) {
        int ex = lofs[tid] - hist[tid];
        lofs[tid] = ex;
        place[tid] = ex;
        int node = b * BNODES + tid;
        if (node < N_NODES) {
            rowptr[node] = b * CAP + ex;
            cnt[node] = hist[tid];
            dis[node] = rsqrtf((float)hist[tid] + 1.0f);
        }
    }
    __syncthreads();
    for (int i = tid; i < count; i += 512) {
        unsigned int v = sl[i];
        int dl = v >> 24;
        int p = atomicAdd(&place[dl], 1);
        reord[p] = v & 0xFFFFFFu;
    }
    __syncthreads();
    for (int i = tid; i < count; i += 512) sl[i] = reord[i];
}

// h1 = x @ W1 via MFMA, pre-scaled by dis[n], packed bf16.
__global__ __launch_bounds__(256) void k_linear1(const float* __restrict__ x,
                                                 const float* __restrict__ W1,
                                                 const float* __restrict__ dis,
                                                 unsigned* __restrict__ hb) {
    __shared__ float dtile[4][16][18];
    int tid = threadIdx.x;
    int lane = tid & 63;
    int w = tid >> 6;
    int tile = blockIdx.x * 4 + w;
    if (tile >= NTILES) return;
    int g = lane >> 4;
    int r = lane & 15;
    const float* xrow = x + (size_t)(tile * 16 + r) * F_INC;
    float4 xa[8], xb[8];
    #pragma unroll
    for (int m = 0; m < 8; ++m) {
        int ks = 32 * m + 8 * g;
        xa[m] = *(const float4*)(xrow + ks);
        xb[m] = *(const float4*)(xrow + ks + 4);
    }
    union { uint4 u; bf16x8 v; } bfr[8];
    #pragma unroll
    for (int m = 0; m < 8; ++m) {
        unsigned uu[4];
        #pragma unroll
        for (int t = 0; t < 4; ++t) {
            int k0 = 32 * m + 8 * g + 2 * t;
            uu[t] = pack_bf2(W1[k0 * HIDC + r], W1[(k0 + 1) * HIDC + r]);
        }
        bfr[m].u = make_uint4(uu[0], uu[1], uu[2], uu[3]);
    }
    f32x4 acc = {0.f, 0.f, 0.f, 0.f};
    #pragma unroll
    for (int m = 0; m < 8; ++m) {
        union { uint4 u; bf16x8 v; } af;
        af.u = make_uint4(pack_bf2(xa[m].x, xa[m].y), pack_bf2(xa[m].z, xa[m].w),
                          pack_bf2(xb[m].x, xb[m].y), pack_bf2(xb[m].z, xb[m].w));
        acc = __builtin_amdgcn_mfma_f32_16x16x32_bf16(af.v, bfr[m].v, acc, 0, 0, 0);
    }
    #pragma unroll
    for (int t = 0; t < 4; ++t) dtile[w][4 * g + t][r] = acc[t];
    __builtin_amdgcn_s_waitcnt(0);
    int q = lane & 7;
    #pragma unroll
    for (int h = 0; h < 2; ++h) {
        int rr = (lane >> 3) + 8 * h;
        int node = tile * 16 + rr;
        float dn = dis[node];
        hb[(size_t)node * 8 + q] =
            pack_bf2(dn * dtile[w][rr][2 * q], dn * dtile[w][rr][2 * q + 1]);
    }
}

// Gather core with cooperative csr reads: lane q loads csr[base+j+q]
// (coalesced 32B per 8-lane group) and broadcasts via shuffle — 1 csr load
// + 8 table loads per 8 edges instead of 8 + 8.
__device__ __forceinline__ void gather_core(int base, int deg, int q, int gb,
                                            const unsigned* __restrict__ csr,
                                            const unsigned* __restrict__ hb,
                                            unsigned sv, float& acc0, float& acc1) {
    acc0 = bflo(sv); acc1 = bfhi(sv);
    int j = 0;
    for (; j + 7 < deg; j += 8) {
        int smine = (int)csr[base + j + q];
        #pragma unroll
        for (int t = 0; t < 8; ++t) {
            int s = __shfl(smine, gb + t, 64);
            unsigned v = hb[(size_t)s * 8 + q];
            acc0 += bflo(v);
            acc1 += bfhi(v);
        }
    }
    for (; j < deg; ++j) {
        int s = csr[base + j];
        unsigned v = hb[(size_t)s * 8 + q];
        acc0 += bflo(v);
        acc1 += bfhi(v);
    }
}

// Layer-1 gather FUSED with bias+ELU+@W2+prescale-pack: writes next bf16 table.
__global__ __launch_bounds__(256) void k_gather_fl1(const int* __restrict__ rowptr,
                                                    const int* __restrict__ cnt,
                                                    const unsigned* __restrict__ csr,
                                                    const float* __restrict__ dis,
                                                    const unsigned* __restrict__ hb,
                                                    const float* __restrict__ b1,
                                                    const float* __restrict__ W2,
                                                    unsigned* __restrict__ hb_out) {
    __shared__ float W2s[HIDC * HIDC];
    __shared__ float b1s[HIDC];
    if (threadIdx.x < HIDC * HIDC) W2s[threadIdx.x] = W2[threadIdx.x];
    if (threadIdx.x < HIDC) b1s[threadIdx.x] = b1[threadIdx.x];
    __syncthreads();
    int idx = blockIdx.x * blockDim.x + threadIdx.x;
    int n = idx >> 3;
    if (n >= N_NODES) return;
    int q = idx & 7;
    int lane = threadIdx.x & 63;
    int gb = lane & 56;
    float acc0, acc1;
    gather_core(rowptr[n], cnt[n], q, gb, csr, hb, hb[(size_t)n * 8 + q], acc0, acc1);
    float dn = dis[n];
    float a0 = elu1(acc0 * dn + b1s[2 * q]);
    float a1 = elu1(acc1 * dn + b1s[2 * q + 1]);
    float h0 = 0.f, h1 = 0.f;
    #pragma unroll
    for (int k2 = 0; k2 < 8; ++k2) {
        float e0 = __shfl(a0, gb + k2, 64);
        float e1 = __shfl(a1, gb + k2, 64);
        h0 += e0 * W2s[(2 * k2) * HIDC + 2 * q]     + e1 * W2s[(2 * k2 + 1) * HIDC + 2 * q];
        h1 += e0 * W2s[(2 * k2) * HIDC + 2 * q + 1] + e1 * W2s[(2 * k2 + 1) * HIDC + 2 * q + 1];
    }
    hb_out[(size_t)n * 8 + q] = pack_bf2(dn * h0, dn * h1);
}

// Layer-2 gather: z2 = elu(agg + b2), stored pre-scaled bf16 (next table).
__global__ __launch_bounds__(256) void k_gather_z(const int* __restrict__ rowptr,
                                                  const int* __restrict__ cnt,
                                                  const unsigned* __restrict__ csr,
                                                  const float* __restrict__ dis,
                                                  const unsigned* __restrict__ hb,
                                                  const float* __restrict__ bias,
                                                  unsigned* __restrict__ outp) {
    int idx = blockIdx.x * blockDim.x + threadIdx.x;
    int n = idx >> 3;
    if (n >= N_NODES) return;
    int q = idx & 7;
    int gb = (threadIdx.x & 63) & 56;
    float acc0, acc1;
    gather_core(rowptr[n], cnt[n], q, gb, csr, hb, hb[(size_t)n * 8 + q], acc0, acc1);
    float dn = dis[n];
    float z0 = elu1(acc0 * dn + bias[2 * q]);
    float z1 = elu1(acc1 * dn + bias[2 * q + 1]);
    outp[(size_t)n * 8 + q] = pack_bf2(dn * z0, dn * z1);
}

// Layer-3 gather FUSED with @W3+bias+ELU+log_softmax: writes out directly.
__global__ __launch_bounds__(256) void k_gather_fin(const int* __restrict__ rowptr,
                                                    const int* __restrict__ cnt,
                                                    const unsigned* __restrict__ csr,
                                                    const float* __restrict__ dis,
                                                    const unsigned* __restrict__ hb,
                                                    const float* __restrict__ W3,
                                                    const float* __restrict__ b3,
                                                    float* __restrict__ out) {
    __shared__ float W3s[HIDC * NCLS];
    __shared__ float b3s[NCLS];
    for (int i = threadIdx.x; i < HIDC * NCLS; i += 256) W3s[i] = W3[i];
    if (threadIdx.x < NCLS) b3s[threadIdx.x] = b3[threadIdx.x];
    __syncthreads();
    int idx = blockIdx.x * blockDim.x + threadIdx.x;
    int n = idx >> 3;
    if (n >= N_NODES) return;
    int q = idx & 7;
    int lane = threadIdx.x & 63;
    int gb = lane & 56;
    float acc0, acc1;
    gather_core(rowptr[n], cnt[n], q, gb, csr, hb, hb[(size_t)n * 8 + q], acc0, acc1);
    float dn = dis[n];
    float g0 = acc0 * dn, g1 = acc1 * dn;
    int j0 = q * 4;
    float r0 = b3s[j0], r1 = b3s[j0 + 1], r2 = b3s[j0 + 2], r3 = b3s[j0 + 3];
    #pragma unroll
    for (int k2 = 0; k2 < 8; ++k2) {
        float e0 = __shfl(g0, gb + k2, 64);
        float e1 = __shfl(g1, gb + k2, 64);
        const float* wa = &W3s[(2 * k2) * NCLS + j0];
        const float* wb = &W3s[(2 * k2 + 1) * NCLS + j0];
        r0 += e0 * wa[0] + e1 * wb[0];
        r1 += e0 * wa[1] + e1 * wb[1];
        r2 += e0 * wa[2] + e1 * wb[2];
        r3 += e0 * wa[3] + e1 * wb[3];
    }
    r0 = elu1(r0); r1 = elu1(r1); r2 = elu1(r2); r3 = elu1(r3);
    float m = fmaxf(fmaxf(r0, r1), fmaxf(r2, r3));
    #pragma unroll
    for (int off = 1; off < 8; off <<= 1) m = fmaxf(m, __shfl_xor(m, off, 64));
    float s = expf(r0 - m) + expf(r1 - m) + expf(r2 - m) + expf(r3 - m);
    #pragma unroll
    for (int off = 1; off < 8; off <<= 1) s += __shfl_xor(s, off, 64);
    float lse = logf(s) + m;
    float4* o = (float4*)(out + (size_t)n * NCLS + j0);
    *o = make_float4(r0 - lse, r1 - lse, r2 - lse, r3 - lse);
}

extern "C" void kernel_launch(void* const* d_in, const int* in_sizes, int n_in,
                              void* d_out, int out_size, void* d_ws, size_t ws_size,
                              hipStream_t stream) {
    const float* x  = (const float*)d_in[0];
    const int*   ei = (const int*)d_in[1];
    const float* W1 = (const float*)d_in[2];
    const float* b1 = (const float*)d_in[3];
    const float* W2 = (const float*)d_in[4];
    const float* b2 = (const float*)d_in[5];
    const float* W3 = (const float*)d_in[6];
    const float* b3 = (const float*)d_in[7];
    float* out = (float*)d_out;
    const int* src = ei;
    const int* dst = ei + N_EDGES;

    int* wi = (int*)d_ws;
    int*          gcur   = wi;                                   // 512
    unsigned int* slab   = (unsigned int*)(wi + 512);            // NBKT*CAP
    int*          rowptr = wi + 512 + NBKT * CAP;                // 102,400
    int*          cnt    = rowptr + 102400;                      // 102,400
    float*        dis    = (float*)(cnt + 102400);               // 102,400
    unsigned*     Bh     = (unsigned*)(dis + 102400);            // 819,200
    unsigned*     Zb     = Bh + 819200;                          // 819,200
    (void)ws_size; (void)n_in; (void)in_sizes; (void)out_size;

    const int GGATH = (int)(((long long)N_NODES * 8 + 255) / 256);   // 3125

    k_zero_cur<<<1, 512, 0, stream>>>(gcur);
    k_bucket<<<NCHUNK, 256, 0, stream>>>(src, dst, gcur, slab);
    k_csr<<<NBKT, 512, 0, stream>>>(gcur, slab, rowptr, cnt, dis);

    // Layer 1: h1 = x@W1 via MFMA (pre-scaled bf16) -> gather+bias+ELU+@W2 -> Zb
    k_linear1<<<GLIN1, 256, 0, stream>>>(x, W1, dis, Bh);
    k_gather_fl1<<<GGATH, 256, 0, stream>>>(rowptr, cnt, slab, dis, Bh, b1, W2, Zb);
    // Layer 2: gather -> z2 = elu(agg+b2) -> Bh
    k_gather_z<<<GGATH, 256, 0, stream>>>(rowptr, cnt, slab, dis, Zb, b2, Bh);
    // Layer 3: gather -> @W3+b3 -> ELU -> log_softmax -> out
    k_gather_fin<<<GGATH, 256, 0, stream>>>(rowptr, cnt, slab, dis, Bh, W3, b3, out);
}